// Round 14
// baseline (168.788 us; speedup 1.0000x reference)
//
#include <hip/hip_runtime.h>
#include <hip/hip_bf16.h>

typedef float floatx4 __attribute__((ext_vector_type(4)));
typedef short bhalf8  __attribute__((ext_vector_type(8)));
typedef unsigned short ush;
typedef unsigned int uint;

#define EPS 1e-5f

constexpr int Bb = 8, S = 256, T = 64, Dc = 100;
constexpr int SH = 255;   // conv2/y2 rows (S-H+1)
constexpr int SO = 254;   // final logit rows
constexpr int CK = 128;   // padded input-channel (K per h-tap)
constexpr int CR = 112;   // padded output-channel rows (7 x 16)
constexpr int LSTR = 136; // LDS row stride in bf16 (272B)

// workspace layout (bytes)
constexpr size_t OFF_U1   = 0;                            // f32[128]
constexpr size_t OFF_S2   = 512;                          // f32[128]
constexpr size_t OFF_W30  = 1024;                         // f32[128]
constexpr size_t OFF_W31  = 1536;                         // f32[128]
constexpr size_t OFF_W2P  = 2048;                         // ush [2][112][128]
constexpr size_t OFF_AQS  = OFF_W2P + 57344;              // f32 [8][255][128]  Aq*s1+u1
constexpr size_t OFF_AQE  = OFF_AQS + (size_t)Bb*SH*CK*4; // f32 [8][255][128]  Aq*s2+u2
constexpr size_t OFF_AKF  = OFF_AQE + (size_t)Bb*SH*CK*4; // f32 [8][16][4][64][8] Ak*s1, MFMA-B order
constexpr size_t OFF_AKEF = OFF_AKF + (size_t)Bb*16*4*64*8*4;  // f32 [8][16][7][64][4] Ak*s2, MFMA-C order
constexpr size_t OFF_Z0   = OFF_AKEF + (size_t)Bb*16*7*64*4*4; // f32 [8][255][256]
constexpr size_t OFF_Z1   = OFF_Z0 + (size_t)Bb*SH*S*4;   // f32 [8][255][256]

constexpr int NAQT = 256;  // Aq tiles: 32 (8-row) x 8 batches
constexpr int NAKT = 256;  // Ak tiles: 32 (8-row) x 8 batches
constexpr int NW2  = 224;  // W2 pack blocks

__device__ __forceinline__ uint pkbf(float lo, float hi) {
    // pack two f32 -> bf16x2 (+0x8000 round, high halves via one v_perm)
    uint a = __float_as_uint(lo) + 0x8000u;
    uint b = __float_as_uint(hi) + 0x8000u;
    return __builtin_amdgcn_perm(b, a, 0x07060302u);
}

// ---------------- k_prep (single launch): W1-in-LDS Aq/Ak tiles + W2 pack + params (unchanged) ----------------
__global__ __launch_bounds__(128) void k_prep(const float* __restrict__ q, const float* __restrict__ kin,
                                              const float* __restrict__ W1, const float* __restrict__ b1,
                                              const float* __restrict__ g1, const float* __restrict__ be1,
                                              const float* __restrict__ m1, const float* __restrict__ var1,
                                              const float* __restrict__ W2, const float* __restrict__ b2,
                                              const float* __restrict__ g2, const float* __restrict__ be2,
                                              const float* __restrict__ m2, const float* __restrict__ var2,
                                              const float* __restrict__ W3,
                                              ush* __restrict__ W2p,
                                              float* __restrict__ U1, float* __restrict__ S2,
                                              float* __restrict__ W30, float* __restrict__ W31,
                                              float* __restrict__ AqS, float* __restrict__ AqE,
                                              float* __restrict__ AkF, float* __restrict__ AkEF) {
    __shared__ float sh[100 * 129 + 9 * 64];   // W1 slab (pad-129, conflict-free) + row buffer
    float* xs = sh + 100 * 129;
    const int bid = blockIdx.x, c = threadIdx.x;

    if (bid >= NAQT + NAKT) {
        int r = bid - NAQT - NAKT;
        if (r < NW2) {                 // W2 pack -> [h][c(112)][cp(128)] bf16, zero-padded
            int idx = r * 128 + c;
            int h = idx / (CR * CK);
            int rem = idx % (CR * CK);
            int cc = rem / CK, cp = rem % CK;
            float v = (cc < Dc && cp < Dc) ? W2[((size_t)cc * Dc + cp) * 2 + h] : 0.f;
            __hip_bfloat16 bv = __float2bfloat16(v);
            W2p[idx] = *reinterpret_cast<ush*>(&bv);
        } else {                        // per-channel params
            float u1 = 0.f, s2 = 0.f, w0 = 0.f, w1 = 0.f;
            if (c < Dc) {
                float sg1 = g1[c] / sqrtf(var1[c] + EPS);
                u1 = be1[c] - m1[c] * sg1;
                s2 = g2[c] / sqrtf(var2[c] + EPS);
                w0 = W3[c * 2 + 0];
                w1 = W3[c * 2 + 1];
            }
            U1[c] = u1; S2[c] = s2; W30[c] = w0; W31[c] = w1;
        }
        return;
    }

    float s1 = 0.f, u1 = 0.f, s2 = 0.f, u2 = 0.f;
    if (c < Dc) {
        s1 = g1[c] / sqrtf(var1[c] + EPS);
        u1 = be1[c] - m1[c] * s1;
        s2 = g2[c] / sqrtf(var2[c] + EPS);
        u2 = (b2[c] - m2[c]) * s2 + be2[c];
    }

    if (bid < NAQT) {                  // ---- Aq 8-row tile ----
        const int tile = bid & 31, b = bid >> 5;
        const int i0 = tile * 8;
        const int nr = (i0 + 8 <= SH) ? 8 : (SH - i0);
        for (int idx = c; idx < 100 * 128; idx += 128) {
            int cc = idx >> 7, k = idx & 127;
            sh[cc * 129 + k] = W1[(size_t)cc * 256 + k];
        }
        for (int idx = c; idx < (nr + 1) * 64; idx += 128)
            xs[idx] = q[((size_t)b * S + i0 + (idx >> 6)) * T + (idx & 63)];
        __syncthreads();
        float acc[8] = {0.f, 0.f, 0.f, 0.f, 0.f, 0.f, 0.f, 0.f};
        if (c < Dc) {
            const float* wr = sh + c * 129;
            #pragma unroll 2
            for (int t = 0; t < 64; ++t) {
                const float w0 = wr[2 * t], w1 = wr[2 * t + 1];
                #pragma unroll
                for (int r = 0; r < 8; ++r)
                    acc[r] = fmaf(xs[r * 64 + t], w0, fmaf(xs[(r + 1) * 64 + t], w1, acc[r]));
            }
        }
        const float b1v = (c < Dc) ? b1[c] : 0.f;
        for (int r = 0; r < nr; ++r) {
            float s = (c < Dc) ? (acc[r] + b1v) : 0.f;
            size_t row = ((size_t)b * SH + i0 + r) * CK + c;
            AqS[row] = s * s1 + u1;
            AqE[row] = s * s2 + u2;
        }
    } else {                           // ---- Ak 8-row tile ----
        const int r0 = bid - NAQT;
        const int tile = r0 & 31, b = r0 >> 5;
        const int j0 = tile * 8;
        for (int idx = c; idx < 100 * 64; idx += 128) {
            int cc = idx >> 6, t = idx & 63;
            const float2 p = reinterpret_cast<const float2*>(W1 + (size_t)cc * 256 + 128)[t];
            sh[cc * 129 + t] = p.x + p.y;
        }
        for (int idx = c; idx < 8 * 64; idx += 128)
            xs[idx] = kin[((size_t)b * S + j0 + (idx >> 6)) * T + (idx & 63)];
        __syncthreads();
        float acc[8] = {0.f, 0.f, 0.f, 0.f, 0.f, 0.f, 0.f, 0.f};
        if (c < Dc) {
            const float* wr = sh + c * 129;
            #pragma unroll 2
            for (int t = 0; t < 64; ++t) {
                const float w = wr[t];
                #pragma unroll
                for (int r = 0; r < 8; ++r)
                    acc[r] = fmaf(xs[r * 64 + t], w, acc[r]);
            }
        }
        const int ks = c >> 5, qq = (c >> 3) & 3, e = c & 7;      // B-frag coords
        const int ct = c >> 4, q2 = (c >> 2) & 3, rr2 = c & 3;    // C-frag coords
        #pragma unroll
        for (int r = 0; r < 8; ++r) {
            const int j = j0 + r;
            const int j16 = j >> 4, ln = j & 15;
            const float s = (c < Dc) ? acc[r] : 0.f;
            AkF[((((size_t)b * 16 + j16) * 4 + ks) * 64 + qq * 16 + ln) * 8 + e] = s * s1;
            if (c < 112)
                AkEF[((((size_t)b * 16 + j16) * 7 + ct) * 64 + q2 * 16 + ln) * 4 + rr2] = s * s2;
        }
    }
}

// ---------------- k_main: 2 rows/block, 16 j/wave; MFMA chains split into two ct-loops (distance-14 ILP) ----------------
__global__ __launch_bounds__(512, 4) void k_main(const float* __restrict__ AqS, const float* __restrict__ AqE,
                                                 const float* __restrict__ AkF, const float* __restrict__ AkEF,
                                                 const ush* __restrict__ W2p,
                                                 const float* __restrict__ U1, const float* __restrict__ S2,
                                                 const float* __restrict__ W30f, const float* __restrict__ W31f,
                                                 float* __restrict__ Z0, float* __restrict__ Z1) {
    __shared__ __align__(16) ush W2s[2 * CR * LSTR];   // both h halves (~61 KB)
    __shared__ __align__(16) float aqsh[3][128];       // Aq rows i0-1, i0, i0+1 (broadcast reads)
    const int tid = threadIdx.x;
    const int wv = tid >> 6, lane = tid & 63, ln = lane & 15, quad = lane >> 4;
    const int rp = blockIdx.x, jt = blockIdx.y, b = blockIdx.z;
    const int i0 = rp * 2;                   // first output row of this block
    const int j16 = jt * 8 + wv;             // this wave's 16-column tile

    floatx4 acc0[7], acc1[7];                // acc0: row i0, acc1: row i0+1
    #pragma unroll
    for (int ct = 0; ct < 7; ++ct) {
        acc0[ct] = (floatx4){0.f, 0.f, 0.f, 0.f};
        acc1[ct] = (floatx4){0.f, 0.f, 0.f, 0.f};
    }

    for (int idx = tid; idx < 2 * CR * 16; idx += 512) {
        int row = idx >> 4, ch = idx & 15;
        *reinterpret_cast<uint4*>(&W2s[row * LSTR + ch * 8]) =
            *reinterpret_cast<const uint4*>(&W2p[row * CK + ch * 8]);
    }
    if (tid < 384) {                          // stage 3 Aq rows
        int r = tid >> 7, cc = tid & 127;
        int gi = i0 - 1 + r;
        const float* src;
        if (gi < 0) src = U1;
        else {
            if (gi > SH - 1) gi = SH - 1;     // clamp (last block's phantom row)
            src = AqS + (size_t)(b * SH + gi) * CK;
        }
        aqsh[r][cc] = src[cc];
    }
    __syncthreads();

    const float m0 = (i0 == 0) ? 0.f : 1.f;   // mask Ak for the conv-pad row
    const float* fA = AkF + ((size_t)(b * 16 + j16) * 4 * 64 + lane) * 8;   // lane*32B coalesced

    float4 ka = *reinterpret_cast<const float4*>(fA);
    float4 kb = *reinterpret_cast<const float4*>(fA + 4);

    #pragma unroll 1
    for (int ks = 0; ks < 4; ++ks) {
        const int k0 = ks * 32 + quad * 8;
        const int kn = ((ks + 1) & 3) * 512;  // rotation prefetch (wraps; branch-free)
        const float4 ka2 = *reinterpret_cast<const float4*>(fA + kn);
        const float4 kb2 = *reinterpret_cast<const float4*>(fA + kn + 4);

        // fragment rows i0-1 (masked), i0, i0+1
        uint4 pm, p0, pp;
        {
            const float4 qa = *reinterpret_cast<const float4*>(&aqsh[0][k0]);
            const float4 qb = *reinterpret_cast<const float4*>(&aqsh[0][k0 + 4]);
            pm.x = pkbf(fmaxf(fmaf(ka.x, m0, qa.x), 0.f), fmaxf(fmaf(ka.y, m0, qa.y), 0.f));
            pm.y = pkbf(fmaxf(fmaf(ka.z, m0, qa.z), 0.f), fmaxf(fmaf(ka.w, m0, qa.w), 0.f));
            pm.z = pkbf(fmaxf(fmaf(kb.x, m0, qb.x), 0.f), fmaxf(fmaf(kb.y, m0, qb.y), 0.f));
            pm.w = pkbf(fmaxf(fmaf(kb.z, m0, qb.z), 0.f), fmaxf(fmaf(kb.w, m0, qb.w), 0.f));
        }
        {
            const float4 qa = *reinterpret_cast<const float4*>(&aqsh[1][k0]);
            const float4 qb = *reinterpret_cast<const float4*>(&aqsh[1][k0 + 4]);
            p0.x = pkbf(fmaxf(qa.x + ka.x, 0.f), fmaxf(qa.y + ka.y, 0.f));
            p0.y = pkbf(fmaxf(qa.z + ka.z, 0.f), fmaxf(qa.w + ka.w, 0.f));
            p0.z = pkbf(fmaxf(qb.x + kb.x, 0.f), fmaxf(qb.y + kb.y, 0.f));
            p0.w = pkbf(fmaxf(qb.z + kb.z, 0.f), fmaxf(qb.w + kb.w, 0.f));
        }
        {
            const float4 qa = *reinterpret_cast<const float4*>(&aqsh[2][k0]);
            const float4 qb = *reinterpret_cast<const float4*>(&aqsh[2][k0 + 4]);
            pp.x = pkbf(fmaxf(qa.x + ka.x, 0.f), fmaxf(qa.y + ka.y, 0.f));
            pp.y = pkbf(fmaxf(qa.z + ka.z, 0.f), fmaxf(qa.w + ka.w, 0.f));
            pp.z = pkbf(fmaxf(qb.x + kb.x, 0.f), fmaxf(qb.y + kb.y, 0.f));
            pp.w = pkbf(fmaxf(qb.z + kb.z, 0.f), fmaxf(qb.w + kb.w, 0.f));
        }
        const bhalf8 fm1 = *reinterpret_cast<bhalf8*>(&pm);
        const bhalf8 f0  = *reinterpret_cast<bhalf8*>(&p0);
        const bhalf8 fp1 = *reinterpret_cast<bhalf8*>(&pp);

        // h=0 taps: 14 independent MFMAs (each acc touched once)
        #pragma unroll
        for (int ct = 0; ct < 7; ++ct) {
            const bhalf8 af0 = *reinterpret_cast<const bhalf8*>(&W2s[(ct * 16 + ln) * LSTR + k0]);
            acc0[ct] = __builtin_amdgcn_mfma_f32_16x16x32_bf16(af0, fm1, acc0[ct], 0, 0, 0);
            acc1[ct] = __builtin_amdgcn_mfma_f32_16x16x32_bf16(af0, f0,  acc1[ct], 0, 0, 0);
        }
        // h=1 taps: another 14; each acc's two updates are 14 MFMAs apart
        #pragma unroll
        for (int ct = 0; ct < 7; ++ct) {
            const bhalf8 af1 = *reinterpret_cast<const bhalf8*>(&W2s[(CR + ct * 16 + ln) * LSTR + k0]);
            acc0[ct] = __builtin_amdgcn_mfma_f32_16x16x32_bf16(af1, f0,  acc0[ct], 0, 0, 0);
            acc1[ct] = __builtin_amdgcn_mfma_f32_16x16x32_bf16(af1, fp1, acc1[ct], 0, 0, 0);
        }
        ka = ka2; kb = kb2;
    }

    // epilogue: both rows; conv3 taps reduced over c via quad-shuffles
    const float* eA = AkEF + ((size_t)(b * 16 + j16) * 7 * 64 + lane) * 4;   // lane*16B coalesced
    #pragma unroll
    for (int row = 0; row < 2; ++row) {
        const int gi = i0 + row;
        const int gic = (gi < SH) ? gi : (SH - 1);
        const float* aqer = AqE + (size_t)(b * SH + gic) * CK;
        const floatx4* acc = row ? acc1 : acc0;
        float z0 = 0.f, z1 = 0.f;
        #pragma unroll
        for (int ct = 0; ct < 7; ++ct) {
            const int c = ct * 16 + (quad << 2);
            const float4 aq  = *reinterpret_cast<const float4*>(aqer + c);
            const float4 ake = *reinterpret_cast<const float4*>(eA + ct * 256);
            const float4 s2  = *reinterpret_cast<const float4*>(S2 + c);
            const float4 w0  = *reinterpret_cast<const float4*>(W30f + c);
            const float4 w1  = *reinterpret_cast<const float4*>(W31f + c);
            const float aqv[4] = {aq.x, aq.y, aq.z, aq.w};
            const float kev[4] = {ake.x, ake.y, ake.z, ake.w};
            const float s2v[4] = {s2.x, s2.y, s2.z, s2.w};
            const float w0v[4] = {w0.x, w0.y, w0.z, w0.w};
            const float w1v[4] = {w1.x, w1.y, w1.z, w1.w};
            #pragma unroll
            for (int r = 0; r < 4; ++r) {
                float ta = fmaxf(fmaf(acc[ct][r], s2v[r], aqv[r] + kev[r]), 0.f);
                z0 = fmaf(ta, w0v[r], z0);
                z1 = fmaf(ta, w1v[r], z1);
            }
        }
        z0 += __shfl_xor(z0, 16, 64); z0 += __shfl_xor(z0, 32, 64);
        z1 += __shfl_xor(z1, 16, 64); z1 += __shfl_xor(z1, 32, 64);
        if (lane < 16 && gi < SH) {
            size_t zi = (size_t)(b * SH + gi) * S + j16 * 16 + lane;
            Z0[zi] = z0; Z1[zi] = z1;
        }
    }
}

// ---------------- softmax + attn@v: one wave per output row (unchanged) ----------------
__global__ __launch_bounds__(256) void k_soft(const float* __restrict__ Z0, const float* __restrict__ Z1,
                                              const float* __restrict__ v,
                                              const float* __restrict__ b3,
                                              float* __restrict__ outp,
                                              float* __restrict__ attnp) {
    __shared__ float attn_s[4][256];
    const int wv = threadIdx.x >> 6, lane = threadIdx.x & 63;
    const int i = blockIdx.x * 4 + wv;
    const int b = blockIdx.y;
    if (i >= SO) return;
    const float b3f = b3[0];
    const size_t zr = (size_t)(b * SH + i) * S;
    const float4 z0 = *reinterpret_cast<const float4*>(Z0 + zr + lane * 4);
    const float4 z1 = *reinterpret_cast<const float4*>(Z1 + zr + S + lane * 4);
    float l0 = (z0.x + z1.x + b3f) * 0.1f;
    float l1 = (z0.y + z1.y + b3f) * 0.1f;
    float l2 = (z0.z + z1.z + b3f) * 0.1f;
    float l3 = (z0.w + z1.w + b3f) * 0.1f;

    float mx = fmaxf(fmaxf(l0, l1), fmaxf(l2, l3));
    #pragma unroll
    for (int o = 1; o < 64; o <<= 1) mx = fmaxf(mx, __shfl_xor(mx, o, 64));
    float e0 = __expf(l0 - mx), e1 = __expf(l1 - mx), e2 = __expf(l2 - mx), e3 = __expf(l3 - mx);
    float sm = e0 + e1 + e2 + e3;
    #pragma unroll
    for (int o = 1; o < 64; o <<= 1) sm += __shfl_xor(sm, o, 64);
    const float inv = 1.f / sm;
    const float a0 = e0 * inv, a1 = e1 * inv, a2 = e2 * inv, a3 = e3 * inv;
    *reinterpret_cast<float4*>(attnp + (size_t)(b * SO + i) * S + lane * 4) = make_float4(a0, a1, a2, a3);
    *reinterpret_cast<float4*>(&attn_s[wv][lane * 4]) = make_float4(a0, a1, a2, a3);
    // same-wave LDS RAW: no barrier needed

    const float* vb = v + (size_t)b * S * T + lane;
    float p0 = 0.f, p1 = 0.f, p2 = 0.f, p3 = 0.f;
    #pragma unroll 4
    for (int j = 0; j < 256; j += 4) {
        p0 = fmaf(attn_s[wv][j],     vb[(size_t)j * T],       p0);
        p1 = fmaf(attn_s[wv][j + 1], vb[(size_t)(j + 1) * T], p1);
        p2 = fmaf(attn_s[wv][j + 2], vb[(size_t)(j + 2) * T], p2);
        p3 = fmaf(attn_s[wv][j + 3], vb[(size_t)(j + 3) * T], p3);
    }
    outp[(size_t)(b * SO + i) * T + lane] = (p0 + p1) + (p2 + p3);
}

extern "C" void kernel_launch(void* const* d_in, const int* in_sizes, int n_in,
                              void* d_out, int out_size, void* d_ws, size_t ws_size,
                              hipStream_t stream) {
    const float* q    = (const float*)d_in[0];
    const float* kin  = (const float*)d_in[1];
    const float* vin  = (const float*)d_in[2];
    const float* W1   = (const float*)d_in[3];
    const float* b1   = (const float*)d_in[4];
    const float* g1   = (const float*)d_in[5];
    const float* be1  = (const float*)d_in[6];
    const float* m1   = (const float*)d_in[7];
    const float* var1 = (const float*)d_in[8];
    const float* W2   = (const float*)d_in[9];
    const float* b2   = (const float*)d_in[10];
    const float* g2   = (const float*)d_in[11];
    const float* be2  = (const float*)d_in[12];
    const float* m2   = (const float*)d_in[13];
    const float* var2 = (const float*)d_in[14];
    const float* W3   = (const float*)d_in[15];
    const float* b3   = (const float*)d_in[16];

    char* ws = (char*)d_ws;
    float* U1   = (float*)(ws + OFF_U1);
    float* S2p  = (float*)(ws + OFF_S2);
    float* W30  = (float*)(ws + OFF_W30);
    float* W31  = (float*)(ws + OFF_W31);
    ush*   W2p  = (ush*)(ws + OFF_W2P);
    float* AqS  = (float*)(ws + OFF_AQS);
    float* AqE  = (float*)(ws + OFF_AQE);
    float* AkF  = (float*)(ws + OFF_AKF);
    float* AkEF = (float*)(ws + OFF_AKEF);
    float* Z0   = (float*)(ws + OFF_Z0);
    float* Z1   = (float*)(ws + OFF_Z1);

    float* outp  = (float*)d_out;
    float* attnp = outp + (size_t)Bb * SO * T;

    k_prep<<<NAQT + NAKT + NW2 + 1, 128, 0, stream>>>(q, kin, W1, b1, g1, be1, m1, var1,
                                                      W2, b2, g2, be2, m2, var2, W3,
                                                      W2p, U1, S2p, W30, W31,
                                                      AqS, AqE, AkF, AkEF);
    k_main<<<dim3(128, 2, Bb), 512, 0, stream>>>(AqS, AqE, AkF, AkEF, W2p, U1, S2p, W30, W31, Z0, Z1);
    k_soft<<<dim3((SO + 3) / 4, Bb), 256, 0, stream>>>(Z0, Z1, vin, b3, outp, attnp);
}

// Round 15
// 159.117 us; speedup vs baseline: 1.0608x; 1.0608x over previous
//
#include <hip/hip_runtime.h>
#include <hip/hip_bf16.h>

typedef float floatx4 __attribute__((ext_vector_type(4)));
typedef short bhalf8  __attribute__((ext_vector_type(8)));
typedef unsigned short ush;
typedef unsigned int uint;

#define EPS 1e-5f

constexpr int Bb = 8, S = 256, T = 64, Dc = 100;
constexpr int SH = 255;   // conv2/y2 rows (S-H+1)
constexpr int SO = 254;   // final logit rows
constexpr int CK = 128;   // padded input-channel (K per h-tap)
constexpr int CR = 112;   // padded output-channel rows (7 x 16)
constexpr int LSTR = 136; // LDS row stride in bf16 (272B)

// workspace layout (bytes)
constexpr size_t OFF_U1   = 0;                            // f32[128]
constexpr size_t OFF_S2   = 512;                          // f32[128]
constexpr size_t OFF_W30  = 1024;                         // f32[128]
constexpr size_t OFF_W31  = 1536;                         // f32[128]
constexpr size_t OFF_W2P  = 2048;                         // ush [2][112][128]
constexpr size_t OFF_AQS  = OFF_W2P + 57344;              // f32 [8][255][128]  Aq*s1+u1
constexpr size_t OFF_AQE  = OFF_AQS + (size_t)Bb*SH*CK*4; // f32 [8][255][128]  Aq*s2+u2
constexpr size_t OFF_AKF  = OFF_AQE + (size_t)Bb*SH*CK*4; // f32 [8][16][4][64][8] Ak*s1, MFMA-B order
constexpr size_t OFF_AKEF = OFF_AKF + (size_t)Bb*16*4*64*8*4;  // f32 [8][16][7][64][4] Ak*s2, MFMA-C order
constexpr size_t OFF_Z0   = OFF_AKEF + (size_t)Bb*16*7*64*4*4; // f32 [8][255][256]
constexpr size_t OFF_Z1   = OFF_Z0 + (size_t)Bb*SH*S*4;   // f32 [8][255][256]

constexpr int NAQT = 256;  // Aq tiles: 32 (8-row) x 8 batches
constexpr int NAKT = 256;  // Ak tiles: 32 (8-row) x 8 batches
constexpr int NW2  = 224;  // W2 pack blocks

__device__ __forceinline__ uint pkbf(float lo, float hi) {
    // pack two f32 -> bf16x2 (+0x8000 round, high halves via one v_perm)
    uint a = __float_as_uint(lo) + 0x8000u;
    uint b = __float_as_uint(hi) + 0x8000u;
    return __builtin_amdgcn_perm(b, a, 0x07060302u);
}

// ---------------- k_prep (single launch): W1-in-LDS Aq/Ak tiles + W2 pack + params ----------------
__global__ __launch_bounds__(128) void k_prep(const float* __restrict__ q, const float* __restrict__ kin,
                                              const float* __restrict__ W1, const float* __restrict__ b1,
                                              const float* __restrict__ g1, const float* __restrict__ be1,
                                              const float* __restrict__ m1, const float* __restrict__ var1,
                                              const float* __restrict__ W2, const float* __restrict__ b2,
                                              const float* __restrict__ g2, const float* __restrict__ be2,
                                              const float* __restrict__ m2, const float* __restrict__ var2,
                                              const float* __restrict__ W3,
                                              ush* __restrict__ W2p,
                                              float* __restrict__ U1, float* __restrict__ S2,
                                              float* __restrict__ W30, float* __restrict__ W31,
                                              float* __restrict__ AqS, float* __restrict__ AqE,
                                              float* __restrict__ AkF, float* __restrict__ AkEF) {
    __shared__ float sh[100 * 129 + 9 * 64];   // W1 slab (pad-129, conflict-free) + row buffer
    float* xs = sh + 100 * 129;
    const int bid = blockIdx.x, c = threadIdx.x;

    if (bid >= NAQT + NAKT) {
        int r = bid - NAQT - NAKT;
        if (r < NW2) {                 // W2 pack -> [h][c(112)][cp(128)] bf16, zero-padded
            int idx = r * 128 + c;
            int h = idx / (CR * CK);
            int rem = idx % (CR * CK);
            int cc = rem / CK, cp = rem % CK;
            float v = (cc < Dc && cp < Dc) ? W2[((size_t)cc * Dc + cp) * 2 + h] : 0.f;
            __hip_bfloat16 bv = __float2bfloat16(v);
            W2p[idx] = *reinterpret_cast<ush*>(&bv);
        } else {                        // per-channel params
            float u1 = 0.f, s2 = 0.f, w0 = 0.f, w1 = 0.f;
            if (c < Dc) {
                float sg1 = g1[c] / sqrtf(var1[c] + EPS);
                u1 = be1[c] - m1[c] * sg1;
                s2 = g2[c] / sqrtf(var2[c] + EPS);
                w0 = W3[c * 2 + 0];
                w1 = W3[c * 2 + 1];
            }
            U1[c] = u1; S2[c] = s2; W30[c] = w0; W31[c] = w1;
        }
        return;
    }

    float s1 = 0.f, u1 = 0.f, s2 = 0.f, u2 = 0.f;
    if (c < Dc) {
        s1 = g1[c] / sqrtf(var1[c] + EPS);
        u1 = be1[c] - m1[c] * s1;
        s2 = g2[c] / sqrtf(var2[c] + EPS);
        u2 = (b2[c] - m2[c]) * s2 + be2[c];
    }

    if (bid < NAQT) {                  // ---- Aq 8-row tile ----
        const int tile = bid & 31, b = bid >> 5;
        const int i0 = tile * 8;
        const int nr = (i0 + 8 <= SH) ? 8 : (SH - i0);
        for (int idx = c; idx < 100 * 128; idx += 128) {
            int cc = idx >> 7, k = idx & 127;
            sh[cc * 129 + k] = W1[(size_t)cc * 256 + k];
        }
        for (int idx = c; idx < (nr + 1) * 64; idx += 128)
            xs[idx] = q[((size_t)b * S + i0 + (idx >> 6)) * T + (idx & 63)];
        __syncthreads();
        float acc[8] = {0.f, 0.f, 0.f, 0.f, 0.f, 0.f, 0.f, 0.f};
        if (c < Dc) {
            const float* wr = sh + c * 129;
            #pragma unroll 2
            for (int t = 0; t < 64; ++t) {
                const float w0 = wr[2 * t], w1 = wr[2 * t + 1];
                #pragma unroll
                for (int r = 0; r < 8; ++r)
                    acc[r] = fmaf(xs[r * 64 + t], w0, fmaf(xs[(r + 1) * 64 + t], w1, acc[r]));
            }
        }
        const float b1v = (c < Dc) ? b1[c] : 0.f;
        for (int r = 0; r < nr; ++r) {
            float s = (c < Dc) ? (acc[r] + b1v) : 0.f;
            size_t row = ((size_t)b * SH + i0 + r) * CK + c;
            AqS[row] = s * s1 + u1;
            AqE[row] = s * s2 + u2;
        }
    } else {                           // ---- Ak 8-row tile ----
        const int r0 = bid - NAQT;
        const int tile = r0 & 31, b = r0 >> 5;
        const int j0 = tile * 8;
        for (int idx = c; idx < 100 * 64; idx += 128) {
            int cc = idx >> 6, t = idx & 63;
            const float2 p = reinterpret_cast<const float2*>(W1 + (size_t)cc * 256 + 128)[t];
            sh[cc * 129 + t] = p.x + p.y;
        }
        for (int idx = c; idx < 8 * 64; idx += 128)
            xs[idx] = kin[((size_t)b * S + j0 + (idx >> 6)) * T + (idx & 63)];
        __syncthreads();
        float acc[8] = {0.f, 0.f, 0.f, 0.f, 0.f, 0.f, 0.f, 0.f};
        if (c < Dc) {
            const float* wr = sh + c * 129;
            #pragma unroll 2
            for (int t = 0; t < 64; ++t) {
                const float w = wr[t];
                #pragma unroll
                for (int r = 0; r < 8; ++r)
                    acc[r] = fmaf(xs[r * 64 + t], w, acc[r]);
            }
        }
        const int ks = c >> 5, qq = (c >> 3) & 3, e = c & 7;      // B-frag coords
        const int ct = c >> 4, q2 = (c >> 2) & 3, rr2 = c & 3;    // C-frag coords
        #pragma unroll
        for (int r = 0; r < 8; ++r) {
            const int j = j0 + r;
            const int j16 = j >> 4, ln = j & 15;
            const float s = (c < Dc) ? acc[r] : 0.f;
            AkF[((((size_t)b * 16 + j16) * 4 + ks) * 64 + qq * 16 + ln) * 8 + e] = s * s1;
            if (c < 112)
                AkEF[((((size_t)b * 16 + j16) * 7 + ct) * 64 + q2 * 16 + ln) * 4 + rr2] = s * s2;
        }
    }
}

// ---------------- k_main: 512 threads/row; W2 + Aq rows in LDS; Ak rotation prefetch; mask for pad row ----------------
__global__ __launch_bounds__(512, 4) void k_main(const float* __restrict__ AqS, const float* __restrict__ AqE,
                                                 const float* __restrict__ AkF, const float* __restrict__ AkEF,
                                                 const ush* __restrict__ W2p,
                                                 const float* __restrict__ U1, const float* __restrict__ S2,
                                                 const float* __restrict__ W30f, const float* __restrict__ W31f,
                                                 float* __restrict__ Z0, float* __restrict__ Z1) {
    __shared__ __align__(16) ush W2s[2 * CR * LSTR];   // both h halves (~61 KB)
    __shared__ __align__(16) float aqsh[2][128];       // the two Aq rows (broadcast reads)
    const int tid = threadIdx.x;
    const int wv = tid >> 6, lane = tid & 63, ln = lane & 15, quad = lane >> 4;
    const int ip = blockIdx.x, b = blockIdx.y;
    const int j16A = wv << 1;

    floatx4 acc0[7], acc1[7];
    #pragma unroll
    for (int ct = 0; ct < 7; ++ct) {
        acc0[ct] = (floatx4){0.f, 0.f, 0.f, 0.f};
        acc1[ct] = (floatx4){0.f, 0.f, 0.f, 0.f};
    }

    for (int idx = tid; idx < 2 * CR * 16; idx += 512) {
        int row = idx >> 4, ch = idx & 15;
        *reinterpret_cast<uint4*>(&W2s[row * LSTR + ch * 8]) =
            *reinterpret_cast<const uint4*>(&W2p[row * CK + ch * 8]);
    }
    {
        const bool pad0 = (ip == 0);
        const float* aq0 = pad0 ? U1 : (AqS + (size_t)(b * SH + ip - 1) * CK);
        const float* aq1 = AqS + (size_t)(b * SH + ip) * CK;
        if (tid < 256) {
            const float* src = (tid < 128) ? aq0 : aq1;
            aqsh[tid >> 7][tid & 127] = src[tid & 127];
        }
    }
    __syncthreads();

    const float m0 = (ip == 0) ? 0.f : 1.f;   // mask Ak for the conv-pad row
    const float* fA = AkF + ((size_t)(b * 16 + j16A) * 4 * 64 + lane) * 8;   // lane*32B coalesced
    const float* fB = fA + 4 * 64 * 8;

    float4 ka = *reinterpret_cast<const float4*>(fA);
    float4 kb = *reinterpret_cast<const float4*>(fA + 4);
    float4 kc = *reinterpret_cast<const float4*>(fB);
    float4 kd = *reinterpret_cast<const float4*>(fB + 4);

    #pragma unroll 1
    for (int ks = 0; ks < 4; ++ks) {
        const int k0 = ks * 32 + quad * 8;
        // prefetch next Ak fragments (wraps on last iter; redundant loads, branch-free)
        const int kn = ((ks + 1) & 3) * 512;
        const float4 ka2 = *reinterpret_cast<const float4*>(fA + kn);
        const float4 kb2 = *reinterpret_cast<const float4*>(fA + kn + 4);
        const float4 kc2 = *reinterpret_cast<const float4*>(fB + kn);
        const float4 kd2 = *reinterpret_cast<const float4*>(fB + kn + 4);
        // ---- h = 0 (Aq row ip-1, masked for pad) ----
        {
            const float4 qa = *reinterpret_cast<const float4*>(&aqsh[0][k0]);
            const float4 qb = *reinterpret_cast<const float4*>(&aqsh[0][k0 + 4]);
            uint4 p, rr;
            p.x  = pkbf(fmaxf(fmaf(ka.x, m0, qa.x), 0.f), fmaxf(fmaf(ka.y, m0, qa.y), 0.f));
            p.y  = pkbf(fmaxf(fmaf(ka.z, m0, qa.z), 0.f), fmaxf(fmaf(ka.w, m0, qa.w), 0.f));
            p.z  = pkbf(fmaxf(fmaf(kb.x, m0, qb.x), 0.f), fmaxf(fmaf(kb.y, m0, qb.y), 0.f));
            p.w  = pkbf(fmaxf(fmaf(kb.z, m0, qb.z), 0.f), fmaxf(fmaf(kb.w, m0, qb.w), 0.f));
            rr.x = pkbf(fmaxf(fmaf(kc.x, m0, qa.x), 0.f), fmaxf(fmaf(kc.y, m0, qa.y), 0.f));
            rr.y = pkbf(fmaxf(fmaf(kc.z, m0, qa.z), 0.f), fmaxf(fmaf(kc.w, m0, qa.w), 0.f));
            rr.z = pkbf(fmaxf(fmaf(kd.x, m0, qb.x), 0.f), fmaxf(fmaf(kd.y, m0, qb.y), 0.f));
            rr.w = pkbf(fmaxf(fmaf(kd.z, m0, qb.z), 0.f), fmaxf(fmaf(kd.w, m0, qb.w), 0.f));
            const bhalf8 bf0 = *reinterpret_cast<bhalf8*>(&p);
            const bhalf8 bf1 = *reinterpret_cast<bhalf8*>(&rr);
            #pragma unroll
            for (int ct = 0; ct < 7; ++ct) {
                const bhalf8 af = *reinterpret_cast<const bhalf8*>(&W2s[(ct * 16 + ln) * LSTR + k0]);
                acc0[ct] = __builtin_amdgcn_mfma_f32_16x16x32_bf16(af, bf0, acc0[ct], 0, 0, 0);
                acc1[ct] = __builtin_amdgcn_mfma_f32_16x16x32_bf16(af, bf1, acc1[ct], 0, 0, 0);
            }
        }
        // ---- h = 1 (Aq row ip) ----
        {
            const float4 qa = *reinterpret_cast<const float4*>(&aqsh[1][k0]);
            const float4 qb = *reinterpret_cast<const float4*>(&aqsh[1][k0 + 4]);
            uint4 p, rr;
            p.x  = pkbf(fmaxf(qa.x + ka.x, 0.f), fmaxf(qa.y + ka.y, 0.f));
            p.y  = pkbf(fmaxf(qa.z + ka.z, 0.f), fmaxf(qa.w + ka.w, 0.f));
            p.z  = pkbf(fmaxf(qb.x + kb.x, 0.f), fmaxf(qb.y + kb.y, 0.f));
            p.w  = pkbf(fmaxf(qb.z + kb.z, 0.f), fmaxf(qb.w + kb.w, 0.f));
            rr.x = pkbf(fmaxf(qa.x + kc.x, 0.f), fmaxf(qa.y + kc.y, 0.f));
            rr.y = pkbf(fmaxf(qa.z + kc.z, 0.f), fmaxf(qa.w + kc.w, 0.f));
            rr.z = pkbf(fmaxf(qb.x + kd.x, 0.f), fmaxf(qb.y + kd.y, 0.f));
            rr.w = pkbf(fmaxf(qb.z + kd.z, 0.f), fmaxf(qb.w + kd.w, 0.f));
            const bhalf8 bf0 = *reinterpret_cast<bhalf8*>(&p);
            const bhalf8 bf1 = *reinterpret_cast<bhalf8*>(&rr);
            #pragma unroll
            for (int ct = 0; ct < 7; ++ct) {
                const bhalf8 af = *reinterpret_cast<const bhalf8*>(&W2s[(CR + ct * 16 + ln) * LSTR + k0]);
                acc0[ct] = __builtin_amdgcn_mfma_f32_16x16x32_bf16(af, bf0, acc0[ct], 0, 0, 0);
                acc1[ct] = __builtin_amdgcn_mfma_f32_16x16x32_bf16(af, bf1, acc1[ct], 0, 0, 0);
            }
        }
        ka = ka2; kb = kb2; kc = kc2; kd = kd2;
    }

    // epilogue
    float z0a = 0.f, z1a = 0.f, z0b = 0.f, z1b = 0.f;
    const float* aqer = AqE + (size_t)(b * SH + ip) * CK;
    const float* eA = AkEF + ((size_t)(b * 16 + j16A) * 7 * 64 + lane) * 4;
    const float* eB = eA + 7 * 64 * 4;
    #pragma unroll
    for (int ct = 0; ct < 7; ++ct) {
        const int c = ct * 16 + (quad << 2);
        const float4 aq  = *reinterpret_cast<const float4*>(aqer + c);
        const float4 aka = *reinterpret_cast<const float4*>(eA + ct * 256);
        const float4 akb = *reinterpret_cast<const float4*>(eB + ct * 256);
        const float4 s2  = *reinterpret_cast<const float4*>(S2 + c);
        const float4 w0  = *reinterpret_cast<const float4*>(W30f + c);
        const float4 w1  = *reinterpret_cast<const float4*>(W31f + c);
        const float aqv[4] = {aq.x, aq.y, aq.z, aq.w};
        const float kav[4] = {aka.x, aka.y, aka.z, aka.w};
        const float kbv[4] = {akb.x, akb.y, akb.z, akb.w};
        const float s2v[4] = {s2.x, s2.y, s2.z, s2.w};
        const float w0v[4] = {w0.x, w0.y, w0.z, w0.w};
        const float w1v[4] = {w1.x, w1.y, w1.z, w1.w};
        #pragma unroll
        for (int r = 0; r < 4; ++r) {
            float ta = fmaxf(fmaf(acc0[ct][r], s2v[r], aqv[r] + kav[r]), 0.f);
            z0a = fmaf(ta, w0v[r], z0a);
            z1a = fmaf(ta, w1v[r], z1a);
            float tb = fmaxf(fmaf(acc1[ct][r], s2v[r], aqv[r] + kbv[r]), 0.f);
            z0b = fmaf(tb, w0v[r], z0b);
            z1b = fmaf(tb, w1v[r], z1b);
        }
    }
    z0a += __shfl_xor(z0a, 16, 64); z0a += __shfl_xor(z0a, 32, 64);
    z1a += __shfl_xor(z1a, 16, 64); z1a += __shfl_xor(z1a, 32, 64);
    z0b += __shfl_xor(z0b, 16, 64); z0b += __shfl_xor(z0b, 32, 64);
    z1b += __shfl_xor(z1b, 16, 64); z1b += __shfl_xor(z1b, 32, 64);
    if (lane < 16) {
        size_t zi = (size_t)(b * SH + ip) * S + wv * 32 + lane;
        Z0[zi] = z0a; Z1[zi] = z1a;
        Z0[zi + 16] = z0b; Z1[zi + 16] = z1b;
    }
}

// ---------------- softmax + attn@v: one wave per output row ----------------
__global__ __launch_bounds__(256) void k_soft(const float* __restrict__ Z0, const float* __restrict__ Z1,
                                              const float* __restrict__ v,
                                              const float* __restrict__ b3,
                                              float* __restrict__ outp,
                                              float* __restrict__ attnp) {
    __shared__ float attn_s[4][256];
    const int wv = threadIdx.x >> 6, lane = threadIdx.x & 63;
    const int i = blockIdx.x * 4 + wv;
    const int b = blockIdx.y;
    if (i >= SO) return;
    const float b3f = b3[0];
    const size_t zr = (size_t)(b * SH + i) * S;
    const float4 z0 = *reinterpret_cast<const float4*>(Z0 + zr + lane * 4);
    const float4 z1 = *reinterpret_cast<const float4*>(Z1 + zr + S + lane * 4);
    float l0 = (z0.x + z1.x + b3f) * 0.1f;
    float l1 = (z0.y + z1.y + b3f) * 0.1f;
    float l2 = (z0.z + z1.z + b3f) * 0.1f;
    float l3 = (z0.w + z1.w + b3f) * 0.1f;

    float mx = fmaxf(fmaxf(l0, l1), fmaxf(l2, l3));
    #pragma unroll
    for (int o = 1; o < 64; o <<= 1) mx = fmaxf(mx, __shfl_xor(mx, o, 64));
    float e0 = __expf(l0 - mx), e1 = __expf(l1 - mx), e2 = __expf(l2 - mx), e3 = __expf(l3 - mx);
    float sm = e0 + e1 + e2 + e3;
    #pragma unroll
    for (int o = 1; o < 64; o <<= 1) sm += __shfl_xor(sm, o, 64);
    const float inv = 1.f / sm;
    const float a0 = e0 * inv, a1 = e1 * inv, a2 = e2 * inv, a3 = e3 * inv;
    *reinterpret_cast<float4*>(attnp + (size_t)(b * SO + i) * S + lane * 4) = make_float4(a0, a1, a2, a3);
    *reinterpret_cast<float4*>(&attn_s[wv][lane * 4]) = make_float4(a0, a1, a2, a3);
    // same-wave LDS RAW: no barrier needed

    const float* vb = v + (size_t)b * S * T + lane;
    float p0 = 0.f, p1 = 0.f, p2 = 0.f, p3 = 0.f;
    #pragma unroll 4
    for (int j = 0; j < 256; j += 4) {
        p0 = fmaf(attn_s[wv][j],     vb[(size_t)j * T],       p0);
        p1 = fmaf(attn_s[wv][j + 1], vb[(size_t)(j + 1) * T], p1);
        p2 = fmaf(attn_s[wv][j + 2], vb[(size_t)(j + 2) * T], p2);
        p3 = fmaf(attn_s[wv][j + 3], vb[(size_t)(j + 3) * T], p3);
    }
    outp[(size_t)(b * SO + i) * T + lane] = (p0 + p1) + (p2 + p3);
}

extern "C" void kernel_launch(void* const* d_in, const int* in_sizes, int n_in,
                              void* d_out, int out_size, void* d_ws, size_t ws_size,
                              hipStream_t stream) {
    const float* q    = (const float*)d_in[0];
    const float* kin  = (const float*)d_in[1];
    const float* vin  = (const float*)d_in[2];
    const float* W1   = (const float*)d_in[3];
    const float* b1   = (const float*)d_in[4];
    const float* g1   = (const float*)d_in[5];
    const float* be1  = (const float*)d_in[6];
    const float* m1   = (const float*)d_in[7];
    const float* var1 = (const float*)d_in[8];
    const float* W2   = (const float*)d_in[9];
    const float* b2   = (const float*)d_in[10];
    const float* g2   = (const float*)d_in[11];
    const float* be2  = (const float*)d_in[12];
    const float* m2   = (const float*)d_in[13];
    const float* var2 = (const float*)d_in[14];
    const float* W3   = (const float*)d_in[15];
    const float* b3   = (const float*)d_in[16];

    char* ws = (char*)d_ws;
    float* U1   = (float*)(ws + OFF_U1);
    float* S2p  = (float*)(ws + OFF_S2);
    float* W30  = (float*)(ws + OFF_W30);
    float* W31  = (float*)(ws + OFF_W31);
    ush*   W2p  = (ush*)(ws + OFF_W2P);
    float* AqS  = (float*)(ws + OFF_AQS);
    float* AqE  = (float*)(ws + OFF_AQE);
    float* AkF  = (float*)(ws + OFF_AKF);
    float* AkEF = (float*)(ws + OFF_AKEF);
    float* Z0   = (float*)(ws + OFF_Z0);
    float* Z1   = (float*)(ws + OFF_Z1);

    float* outp  = (float*)d_out;
    float* attnp = outp + (size_t)Bb * SO * T;

    k_prep<<<NAQT + NAKT + NW2 + 1, 128, 0, stream>>>(q, kin, W1, b1, g1, be1, m1, var1,
                                                      W2, b2, g2, be2, m2, var2, W3,
                                                      W2p, U1, S2p, W30, W31,
                                                      AqS, AqE, AkF, AkEF);
    k_main<<<dim3(SH, Bb), 512, 0, stream>>>(AqS, AqE, AkF, AkEF, W2p, U1, S2p, W30, W31, Z0, Z1);
    k_soft<<<dim3((SO + 3) / 4, Bb), 256, 0, stream>>>(Z0, Z1, vin, b3, outp, attnp);
}